// Round 4
// baseline (3598.527 us; speedup 1.0000x reference)
//
#include <hip/hip_runtime.h>
#include <hip/hip_bf16.h>
#include <math.h>

// GGNN: N=50000 nodes, E=400000 edges, G=64 graphs, IN=64, OUT=128, 4 etypes, 8 steps.
// R9: edge-parallel aggregation via LDS float atomics.
//   hx[N][256] fp16: cols 0..127 = ab (aggregated msg), cols 128..255 = hb (h shadow).
//   k_agg_gemm (32-row tiles, 512 thr): s-tile fp32 in LDS (32x4x128 = 64KB);
//     gather loops flat over the tile's contiguous (dst,etype)-sorted edge range,
//     1 edge/wave/iter, all 64 lanes on the same edge (f16x2/lane, coalesced 256B),
//     LDS atomicAdd fp32. No serial segment walk, no divergence. Then in-place
//     fp32->fp16 convert and K=512 MFMA (W_cat), + cnt*bs epilogue -> ab half.
//   k_gates_gru (32-row tiles, 512 thr, ~37KB LDS -> 4 blocks/CU): wave (rg,g)
//     computes gate g for 16 rows; gates via LDS; GRU pointwise; writes h + hb half.

#define NN 50000
#define NE 400000
#define NG 64
#define IND 64
#define OD 128
#define NN4 (NN * 4)
#define RC 8      // readout chunks per graph

typedef _Float16 f16x8 __attribute__((ext_vector_type(8)));
typedef _Float16 f16x4 __attribute__((ext_vector_type(4)));
typedef _Float16 f16x2 __attribute__((ext_vector_type(2)));
typedef float f32x4 __attribute__((ext_vector_type(4)));

__device__ inline unsigned short f2h(float x) {
    _Float16 hv = (_Float16)x;
    unsigned short u;
    __builtin_memcpy(&u, &hv, 2);
    return u;
}

// ---------------- fp32 -> fp16 weight conversion (Ws only) ----------------
__global__ void k_cvt(const float* __restrict__ s, unsigned short* __restrict__ d, int n) {
    int i = blockIdx.x * 256 + threadIdx.x;
    if (i < n) d[i] = f2h(s[i]);
}

// ---------------- pack GRU weights ----------------
// Wpk = [R(128x256) | Z(128x256) | IN(128x128) | HN(128x128)] (halfs)
// R row o = [W_ih[o][:] | W_hh[o][:]], Z row o = [W_ih[128+o][:] | W_hh[128+o][:]]
// IN row o = W_ih[256+o][:], HN row o = W_hh[256+o][:]
// bpk[0..255] = b_ih+b_hh (r,z), bpk[256..383] = b_ih[256..], bpk[384..511] = b_hh[256..]
__global__ void k_pack(const float* __restrict__ Wih, const float* __restrict__ Whh,
                       const float* __restrict__ bih, const float* __restrict__ bhh,
                       unsigned short* __restrict__ Wpk, float* __restrict__ bpk) {
    int i = blockIdx.x * 256 + threadIdx.x;
    if (i < 65536) {                       // R,Z block: o 0..255, k 0..255
        int o = i >> 8, k = i & 255;
        float v = (k < 128) ? Wih[o * 128 + k] : Whh[o * 128 + (k - 128)];
        Wpk[i] = f2h(v);
    } else if (i < 98304) {                // IN,HN block
        int j = i - 65536;
        int o = j >> 7, k = j & 127;       // o 0..255: 0..127 IN, 128..255 HN
        float v = (o < 128) ? Wih[(256 + o) * 128 + k] : Whh[(256 + (o - 128)) * 128 + k];
        Wpk[i] = f2h(v);
    }
    if (i < 512) {
        float b;
        if (i < 256) b = bih[i] + bhh[i];
        else if (i < 384) b = bih[i];
        else b = bhh[i - 128];
        bpk[i] = b;
    }
}

// ---------------- init h = [node_features | 0] (fp32 + fp16 shadow in hx) -------------
__global__ void k_init_h(const float* __restrict__ nf, float* __restrict__ h,
                         unsigned short* __restrict__ hx) {
    int i = blockIdx.x * 256 + threadIdx.x;
    if (i >= NN * OD) return;
    int n = i >> 7, d = i & 127;
    float v = (d < IND) ? nf[n * IND + d] : 0.f;
    h[i] = v;
    hx[(size_t)n * 256 + 128 + d] = f2h(v);
}

// ---------------- (dst, etype) CSR build: 200000 segments ----------------
__global__ void k_count(const int* __restrict__ dst, const int* __restrict__ et,
                        int* __restrict__ deg4) {
    int e = blockIdx.x * 256 + threadIdx.x;
    if (e < NE) atomicAdd(&deg4[dst[e] * 4 + et[e]], 1);
}

__global__ void k_scan1(const int* __restrict__ deg, int* __restrict__ rowp,
                        int* __restrict__ bsum, int n) {
    __shared__ int buf[1024];
    int tid = threadIdx.x;
    int i = blockIdx.x * 1024 + tid;
    int v = (i < n) ? deg[i] : 0;
    buf[tid] = v;
    __syncthreads();
    for (int off = 1; off < 1024; off <<= 1) {
        int t = (tid >= off) ? buf[tid - off] : 0;
        __syncthreads();
        buf[tid] += t;
        __syncthreads();
    }
    if (i < n) rowp[i + 1] = buf[tid];
    if (tid == 1023) bsum[blockIdx.x] = buf[tid];
}

__global__ void k_scan2(int* __restrict__ bsum, int nb) {
    __shared__ int buf[256];
    int tid = threadIdx.x;
    int v = (tid < nb) ? bsum[tid] : 0;
    buf[tid] = v;
    __syncthreads();
    for (int off = 1; off < 256; off <<= 1) {
        int t = (tid >= off) ? buf[tid - off] : 0;
        __syncthreads();
        buf[tid] += t;
        __syncthreads();
    }
    if (tid < nb) bsum[tid] = buf[tid] - v;   // exclusive
}

__global__ void k_scan3(const int* __restrict__ deg, const int* __restrict__ bsum,
                        int* __restrict__ rowp, int* __restrict__ cursor, int n) {
    int i = blockIdx.x * 256 + threadIdx.x;
    if (i >= n) return;
    int incl = rowp[i + 1] + bsum[i >> 10];
    rowp[i + 1] = incl;
    cursor[i] = incl - deg[i];
    if (i == 0) rowp[0] = 0;
}

__global__ void k_fill(const int* __restrict__ src, const int* __restrict__ dst,
                       const int* __restrict__ et, int* __restrict__ cursor,
                       int* __restrict__ esrc, int* __restrict__ edst4) {
    int e = blockIdx.x * 256 + threadIdx.x;
    if (e < NE) {
        int slot = dst[e] * 4 + et[e];
        int pos = atomicAdd(&cursor[slot], 1);
        esrc[pos] = src[e];
        edst4[pos] = slot;
    }
}

// ---------------- graph CSR build (by graph id), for readout ----------------
__global__ void k_gcount(const int* __restrict__ gid, int* __restrict__ gdeg) {
    __shared__ int c[NG];
    int tid = threadIdx.x;
    if (tid < NG) c[tid] = 0;
    __syncthreads();
    int n = blockIdx.x * 1024 + tid;
    if (n < NN) atomicAdd(&c[gid[n]], 1);
    __syncthreads();
    if (tid < NG && c[tid] > 0) atomicAdd(&gdeg[tid], c[tid]);
}

__global__ void k_gscan(const int* __restrict__ gdeg, int* __restrict__ growp,
                        int* __restrict__ gcur) {
    __shared__ int buf[NG];
    int tid = threadIdx.x;
    int v = gdeg[tid];
    buf[tid] = v;
    __syncthreads();
    for (int off = 1; off < NG; off <<= 1) {
        int t = (tid >= off) ? buf[tid - off] : 0;
        __syncthreads();
        buf[tid] += t;
        __syncthreads();
    }
    growp[tid + 1] = buf[tid];
    gcur[tid] = buf[tid] - v;
    if (tid == 0) growp[0] = 0;
}

__global__ void k_gfill(const int* __restrict__ gid, int* __restrict__ gcur,
                        int* __restrict__ nlist) {
    __shared__ int lcnt[NG];
    __shared__ int lbase[NG];
    int tid = threadIdx.x;
    if (tid < NG) lcnt[tid] = 0;
    __syncthreads();
    int n = blockIdx.x * 1024 + tid;
    int g = -1, rank = 0;
    if (n < NN) { g = gid[n]; rank = atomicAdd(&lcnt[g], 1); }
    __syncthreads();
    if (tid < NG && lcnt[tid] > 0) lbase[tid] = atomicAdd(&gcur[tid], lcnt[tid]);
    __syncthreads();
    if (n < NN) nlist[lbase[g] + rank] = n;
}

// ---------------- fused aggregate + K=512 GEMM -> ab (hx cols 0..127) ----------------
// 512 thr (8 waves), 32 dst rows/tile (grid 1563). Edge-parallel gather:
// wave w takes edges ebeg+w, +8, ...; all 64 lanes on one edge (f16x2/lane, 256B
// coalesced); LDS atomicAdd fp32 into s32[slot-local][dim]. Then in-place fp32->fp16
// and K=512 MFMA: wave w -> (rt=w&1, col-tiles (w>>1)*2..+2), acc 2 f32x4.
__global__ __launch_bounds__(512) void k_agg_gemm(
    const unsigned short* __restrict__ hx,    // read cols 128..255 (hb)
    const int* __restrict__ rowp4, const int* __restrict__ esrc,
    const int* __restrict__ edst4,
    const int* __restrict__ deg4,
    const unsigned short* __restrict__ Wsb,   // 4 * 128*128 fp16 (out x in)
    const float* __restrict__ bs,             // 4 * 128 fp32
    unsigned short* __restrict__ hxw) {       // write cols 0..127 (ab)
    __shared__ float s32[32 * 4 * 128];       // 64 KB: [local=(v-m0)*4+t][dim]
    __shared__ float Bsb[512];

    const int tid = threadIdx.x;
    const int m0 = blockIdx.x * 32;
    const int w = tid >> 6;
    const int lane = tid & 63;

    Bsb[tid] = bs[tid];
#pragma unroll
    for (int i = tid; i < 16384; i += 512) s32[i] = 0.f;
    __syncthreads();

    // edge-parallel gather over the tile's contiguous edge range
    {
        const int rend = (m0 + 32 <= NN ? m0 + 32 : NN) * 4;
        const int ebeg = rowp4[m0 * 4];
        const int eend = rowp4[rend];
        const int base4 = m0 * 4;
        for (int e = ebeg + w; e < eend; e += 8) {
            int srcn = esrc[e];
            int local = edst4[e] - base4;          // 0..127
            f16x2 v = *(const f16x2*)&hx[(size_t)srcn * 256 + 128 + lane * 2];
            atomicAdd(&s32[local * 128 + lane * 2], (float)v[0]);
            atomicAdd(&s32[local * 128 + lane * 2 + 1], (float)v[1]);
        }
    }
    __syncthreads();

    // in-place fp32 [32][512] -> fp16 [32][520] (pad 8 halfs/row)
    unsigned short* Sh = (unsigned short*)s32;
    {
        int row = tid >> 4, ch = tid & 15;
        float tmp[32];
        const float* sp = &s32[row * 512 + ch * 32];
#pragma unroll
        for (int k = 0; k < 32; ++k) tmp[k] = sp[k];
        __syncthreads();
        unsigned short* dp = &Sh[row * 520 + ch * 32];
#pragma unroll
        for (int k = 0; k < 32; ++k) dp[k] = f2h(tmp[k]);
    }
    __syncthreads();

    // K=512 MFMA: wave w -> rt = w&1 (16 rows), col-tiles ctb..ctb+1
    const int lr = lane & 15;
    const int q = lane >> 4;
    const int rt = w & 1;
    const int ctb = (w >> 1) * 2;

    f32x4 acc[2];
    acc[0] = (f32x4){0.f, 0.f, 0.f, 0.f};
    acc[1] = (f32x4){0.f, 0.f, 0.f, 0.f};

#pragma unroll
    for (int ks = 0; ks < 16; ++ks) {
        int t = ks >> 2, ksl = ks & 3;
        f16x8 af = *(const f16x8*)&Sh[(rt * 16 + lr) * 520 + ks * 32 + q * 8];
        const unsigned short* Wt = Wsb + t * 16384;
#pragma unroll
        for (int j = 0; j < 2; ++j) {
            int nt = ctb + j;
            f16x8 bf = *(const f16x8*)&Wt[(nt * 16 + lr) * 128 + ksl * 32 + q * 8];
            acc[j] = __builtin_amdgcn_mfma_f32_16x16x32_f16(af, bf, acc[j], 0, 0, 0);
        }
    }

    // epilogue: + sum_t cnt*bs, fp16 store into ab half
    int rowbase = m0 + rt * 16 + q * 4;
#pragma unroll
    for (int rr = 0; rr < 4; ++rr) {
        int n2 = rowbase + rr;
        if (n2 < NN) {
            int4 c = *(const int4*)&deg4[n2 * 4];
            unsigned short* arow = hxw + (size_t)n2 * 256;
#pragma unroll
            for (int j = 0; j < 2; ++j) {
                int col = (ctb + j) * 16 + lr;
                float v = acc[j][rr]
                        + c.x * Bsb[col] + c.y * Bsb[128 + col]
                        + c.z * Bsb[256 + col] + c.w * Bsb[384 + col];
                arow[col] = f2h(v);
            }
        }
    }
}

// ---------------- fused gates GEMM + GRU (512 thr, 32 rows, ~37KB LDS) ---------------
// Wave (rg = w>>2, g = w&3): gate g for rows rg*16..+16 -> acc[8] (32 VGPR).
// g=0:R (K=256), 1:Z (K=256), 2:IN (K=128, ab), 3:HN (K=128, hb).
// Gates -> LDS fp16 (R,Z post-sigmoid; IN,HN pre-tanh, biases folded), then GRU
// pointwise (8 elems/thread), write h fp32 + hb half of hx.
__global__ __launch_bounds__(512) void k_gates_gru(
    const unsigned short* __restrict__ hx,
    const unsigned short* __restrict__ Wpk,   // packed: R|Z (256-K) then IN|HN (128-K)
    const float* __restrict__ bpk,            // 512 packed biases
    float* __restrict__ h,
    unsigned short* __restrict__ hxw) {
    // phase 1: As[2][32][136] (8704 halfs); phase 2: G[4][32][136] (17408 halfs)
    __shared__ unsigned short LS[4 * 32 * 136];   // 34816 B
    __shared__ float Bsb[512];

    const int tid = threadIdx.x;
    const int m0 = blockIdx.x * 32;

    Bsb[tid] = bpk[tid];

    const uint4* H4 = (const uint4*)hx;   // 32 uint4 per 256-half row
#pragma unroll
    for (int it = 0; it < 2; ++it) {
        int i = tid + it * 512;           // 0..1023
        int row = i >> 5, qq = i & 31;
        int nn = m0 + row;
        uint4 v = (nn < NN) ? H4[(size_t)nn * 32 + qq] : make_uint4(0u, 0u, 0u, 0u);
        *(uint4*)&LS[(qq >> 4) * 4352 + row * 136 + (qq & 15) * 8] = v;
    }
    __syncthreads();

    const int lane = tid & 63;
    const int w = tid >> 6;
    const int lr = lane & 15;
    const int q = lane >> 4;
    const int rg = w >> 2;       // row-group 0..1 (16 rows)
    const int g = w & 3;         // gate: 0=R 1=Z 2=IN 3=HN

    f32x4 acc[8];
#pragma unroll
    for (int nt = 0; nt < 8; ++nt) acc[nt] = (f32x4){0.f, 0.f, 0.f, 0.f};

    if (g < 2) {   // R / Z: K=256 over [ab|hb]
        const unsigned short* Wg = Wpk + g * 32768;
#pragma unroll
        for (int ks = 0; ks < 8; ++ks) {
            int chunk = ks >> 2, ksl = ks & 3;
            f16x8 af = *(const f16x8*)&LS[chunk * 4352
                       + (rg * 16 + lr) * 136 + ksl * 32 + q * 8];
#pragma unroll
            for (int nt = 0; nt < 8; ++nt) {
                f16x8 bf = *(const f16x8*)&Wg[(nt * 16 + lr) * 256 + ks * 32 + q * 8];
                acc[nt] = __builtin_amdgcn_mfma_f32_16x16x32_f16(af, bf, acc[nt], 0, 0, 0);
            }
        }
    } else {       // IN (chunk 0 = ab) / HN (chunk 1 = hb): K=128
        const int chunk = g - 2;
        const unsigned short* Wg = Wpk + 65536 + chunk * 16384;
#pragma unroll
        for (int ks = 0; ks < 4; ++ks) {
            f16x8 af = *(const f16x8*)&LS[chunk * 4352
                       + (rg * 16 + lr) * 136 + ks * 32 + q * 8];
#pragma unroll
            for (int nt = 0; nt < 8; ++nt) {
                f16x8 bf = *(const f16x8*)&Wg[(nt * 16 + lr) * 128 + ks * 32 + q * 8];
                acc[nt] = __builtin_amdgcn_mfma_f32_16x16x32_f16(af, bf, acc[nt], 0, 0, 0);
            }
        }
    }
    __syncthreads();   // all MFMA done; As region dead, reuse LS for gates

    // store gate tile to LDS (fp16), bias folded; sigmoid for R/Z
    {
        const int gb = g * 4352;
        const int bofs = g * 128;
        int rowb = rg * 16 + q * 4;
#pragma unroll
        for (int rr = 0; rr < 4; ++rr) {
            int row = rowb + rr;
#pragma unroll
            for (int nt = 0; nt < 8; ++nt) {
                int col = nt * 16 + lr;
                float v = acc[nt][rr] + Bsb[bofs + col];
                if (g < 2) v = 1.f / (1.f + __expf(-v));
                LS[gb + row * 136 + col] = f2h(v);
            }
        }
    }
    __syncthreads();

    // GRU pointwise: thread -> (row = tid>>4, cols (tid&15)*8 .. +8)
    {
        int row = tid >> 4;
        int c = (tid & 15) * 8;
        int n2 = m0 + row;
        if (n2 < NN) {
            float* hrow = h + (size_t)n2 * OD;
            unsigned short* hbrow = hxw + (size_t)n2 * 256 + 128;
            const int rb = row * 136 + c;
            f16x8 Rv = *(const f16x8*)&LS[rb];
            f16x8 Zv = *(const f16x8*)&LS[4352 + rb];
            f16x8 Iv = *(const f16x8*)&LS[8704 + rb];
            f16x8 Hv = *(const f16x8*)&LS[13056 + rb];
            float4 h0 = *(const float4*)&hrow[c];
            float4 h1 = *(const float4*)&hrow[c + 4];
            float hold[8] = {h0.x, h0.y, h0.z, h0.w, h1.x, h1.y, h1.z, h1.w};
            float hn8[8];
            f16x8 hb8;
#pragma unroll
            for (int k = 0; k < 8; ++k) {
                float R = (float)Rv[k], Z = (float)Zv[k];
                float NV = tanhf((float)Iv[k] + R * (float)Hv[k]);
                float v = (1.f - Z) * NV + Z * hold[k];
                hn8[k] = v;
                hb8[k] = (_Float16)v;
            }
            *(float4*)&hrow[c]     = make_float4(hn8[0], hn8[1], hn8[2], hn8[3]);
            *(float4*)&hrow[c + 4] = make_float4(hn8[4], hn8[5], hn8[6], hn8[7]);
            *(f16x8*)&hbrow[c] = hb8;
        }
    }
}

// ---------------- graph readout: register acc over graph-sorted node list ------------
__global__ void k_readout(const float* __restrict__ h, const float* __restrict__ nf,
                          const int* __restrict__ nlist, const int* __restrict__ growp,
                          float* __restrict__ partial) {
    int g = blockIdx.x >> 3, c = blockIdx.x & (RC - 1);
    int d = threadIdx.x;
    int s = growp[g], e = growp[g + 1], len = e - s;
    int i0 = s + (int)((long long)len * c / RC);
    int i1 = s + (int)((long long)len * (c + 1) / RC);
    float acc = 0.f;
    for (int i = i0; i < i1; ++i) {
        int n = nlist[i];
        acc += (d < OD) ? h[(size_t)n * OD + d] : nf[(size_t)n * IND + (d - OD)];
    }
    partial[(size_t)blockIdx.x * 192 + d] = acc;
}

__global__ void k_reduce(const float* __restrict__ partial, float* __restrict__ feats) {
    int i = blockIdx.x * 256 + threadIdx.x;
    if (i >= NG * 192) return;
    int g = i / 192, d = i % 192;
    float s = 0.f;
    for (int c = 0; c < RC; ++c) s += partial[(size_t)(g * RC + c) * 192 + d];
    feats[i] = s;
}

__global__ void k_final(const float* __restrict__ feats, const float* __restrict__ W_cls,
                        const float* __restrict__ b_cls, float* __restrict__ out) {
    int g = threadIdx.x;
    if (g >= NG) return;
    float acc = b_cls[0];
    for (int d = 0; d < 192; ++d) acc += feats[g * 192 + d] * W_cls[d];
    out[g] = 1.f / (1.f + __expf(-acc));
}

extern "C" void kernel_launch(void* const* d_in, const int* in_sizes, int n_in,
                              void* d_out, int out_size, void* d_ws, size_t ws_size,
                              hipStream_t stream) {
    const float* nf    = (const float*)d_in[0];
    const int*   src   = (const int*)d_in[1];
    const int*   dst   = (const int*)d_in[2];
    const int*   et    = (const int*)d_in[3];
    const int*   gid   = (const int*)d_in[4];
    const float* Ws    = (const float*)d_in[5];
    const float* bs    = (const float*)d_in[6];
    const float* W_ih  = (const float*)d_in[7];
    const float* W_hh  = (const float*)d_in[8];
    const float* b_ih  = (const float*)d_in[9];
    const float* b_hh  = (const float*)d_in[10];
    const float* W_cls = (const float*)d_in[11];
    const float* b_cls = (const float*)d_in[12];
    float* out = (float*)d_out;

    char* ws = (char*)d_ws;
    size_t off = 0;
    auto alloc = [&](size_t bytes) -> void* {
        off = (off + 255) & ~(size_t)255;
        void* p = ws + off;
        off += bytes;
        return p;
    };
    float*          h    = (float*)alloc((size_t)NN * OD * 4);              // 25.6 MB
    unsigned short* hx   = (unsigned short*)alloc((size_t)NN * 256 * 2);    // 25.6 MB
    int*   deg4    = (int*)alloc((size_t)NN4 * 4);
    int*   rowp4   = (int*)alloc((size_t)(NN4 + 1) * 4);
    int*   cursor4 = (int*)alloc((size_t)NN4 * 4);
    int*   esrc    = (int*)alloc((size_t)NE * 4);
    int*   edst4   = (int*)alloc((size_t)NE * 4);
    int*   bsum    = (int*)alloc(256 * 4);
    int*   gdeg    = (int*)alloc(NG * 4);
    int*   growp   = (int*)alloc((NG + 1) * 4);
    int*   gcur    = (int*)alloc(NG * 4);
    int*   nlist   = (int*)alloc((size_t)NN * 4);
    float* feats   = (float*)alloc((size_t)NG * 192 * 4);
    float* partial = (float*)alloc((size_t)NG * RC * 192 * 4);              // 393 KB
    unsigned short* wsb = (unsigned short*)alloc((size_t)4 * 16384 * 2);
    unsigned short* Wpk = (unsigned short*)alloc((size_t)98304 * 2);
    float*          bpk = (float*)alloc(512 * 4);
    (void)ws_size; (void)in_sizes; (void)n_in; (void)out_size;

    hipMemsetAsync(deg4, 0, (size_t)NN4 * 4, stream);
    hipMemsetAsync(gdeg, 0, NG * 4, stream);

    k_cvt<<<(4 * 16384 + 255) / 256, 256, 0, stream>>>(Ws, wsb, 4 * 16384);
    k_pack<<<(98304 + 255) / 256, 256, 0, stream>>>(W_ih, W_hh, b_ih, b_hh, Wpk, bpk);

    k_init_h<<<(NN * OD + 255) / 256, 256, 0, stream>>>(nf, h, hx);

    // (dst, etype) CSR
    k_count<<<(NE + 255) / 256, 256, 0, stream>>>(dst, et, deg4);
    const int nb4 = (NN4 + 1023) / 1024;   // 196
    k_scan1<<<nb4, 1024, 0, stream>>>(deg4, rowp4, bsum, NN4);
    k_scan2<<<1, 256, 0, stream>>>(bsum, nb4);
    k_scan3<<<(NN4 + 255) / 256, 256, 0, stream>>>(deg4, bsum, rowp4, cursor4, NN4);
    k_fill<<<(NE + 255) / 256, 256, 0, stream>>>(src, dst, et, cursor4, esrc, edst4);

    // graph CSR (readout)
    const int nbn = (NN + 1023) / 1024;    // 49
    k_gcount<<<nbn, 1024, 0, stream>>>(gid, gdeg);
    k_gscan<<<1, NG, 0, stream>>>(gdeg, growp, gcur);
    k_gfill<<<nbn, 1024, 0, stream>>>(gid, gcur, nlist);

    const int mt32 = (NN + 31) / 32;   // 1563 node tiles
    for (int s = 0; s < 8; ++s) {
        k_agg_gemm<<<mt32, 512, 0, stream>>>(hx, rowp4, esrc, edst4, deg4, wsb, bs, hx);
        k_gates_gru<<<mt32, 512, 0, stream>>>(hx, Wpk, bpk, h, hx);
    }

    k_readout<<<NG * RC, 192, 0, stream>>>(h, nf, nlist, growp, partial);
    k_reduce<<<(NG * 192 + 255) / 256, 256, 0, stream>>>(partial, feats);
    k_final<<<1, 64, 0, stream>>>(feats, W_cls, b_cls, out);
}

// Round 5
// 1778.600 us; speedup vs baseline: 2.0232x; 2.0232x over previous
//
#include <hip/hip_runtime.h>
#include <hip/hip_bf16.h>
#include <math.h>

// GGNN: N=50000 nodes, E=400000 edges, G=64 graphs, IN=64, OUT=128, 4 etypes, 8 steps.
// R10: register-gather aggregation (no atomics, no barriers in gather).
//   hx[N][256] fp16: cols 0..127 = ab (aggregated msg), cols 128..255 = hb (h shadow).
//   k_agg_gemm (1024 thr, 32 rows): one node per 32-lane half-wave, 4 dims/lane;
//     walks the node's contiguous edge range (epk = src|et<<16) with 2-way unrolled
//     independent f16x4 loads, etype-predicated f32 reg accumulators acc[4][4].
//     One barrier -> s-tile LDS fp16 [32][520] -> K=512 MFMA vs Wcat[128][512]
//     (16 waves x 1 f32x4 acc), + cnt*bs epilogue -> ab half of hx.
//   k_gates_gru (1024 thr, 64 rows, ~72KB LDS -> 2 blk/CU, 32 waves = 100% occ):
//     wave (rg,g): gate g for 16 rows, acc[8] (32 VGPR); gates via LDS; GRU
//     pointwise in-block; writes h fp32 + hb half. No O table.

#define NN 50000
#define NE 400000
#define NG 64
#define IND 64
#define OD 128
#define NN4 (NN * 4)
#define RC 8      // readout chunks per graph

typedef _Float16 f16x8 __attribute__((ext_vector_type(8)));
typedef _Float16 f16x4 __attribute__((ext_vector_type(4)));
typedef _Float16 f16x2 __attribute__((ext_vector_type(2)));
typedef float f32x4 __attribute__((ext_vector_type(4)));

__device__ inline unsigned short f2h(float x) {
    _Float16 hv = (_Float16)x;
    unsigned short u;
    __builtin_memcpy(&u, &hv, 2);
    return u;
}

// ---------------- Ws fp32 -> concatenated fp16 Wcat[o][t*128+k] ----------------
__global__ void k_cvtws(const float* __restrict__ Ws, unsigned short* __restrict__ Wcat) {
    int i = blockIdx.x * 256 + threadIdx.x;   // 65536
    if (i >= 65536) return;
    int o = i >> 9, col = i & 511;
    int t = col >> 7, k = col & 127;
    Wcat[i] = f2h(Ws[t * 16384 + o * 128 + k]);
}

// ---------------- pack GRU weights ----------------
// Wpk = [R(128x256) | Z(128x256) | IN(128x128) | HN(128x128)] (halfs)
// bpk[0..255] = b_ih+b_hh (r,z), bpk[256..383] = b_ih[256..], bpk[384..511] = b_hh[256..]
__global__ void k_pack(const float* __restrict__ Wih, const float* __restrict__ Whh,
                       const float* __restrict__ bih, const float* __restrict__ bhh,
                       unsigned short* __restrict__ Wpk, float* __restrict__ bpk) {
    int i = blockIdx.x * 256 + threadIdx.x;
    if (i < 65536) {                       // R,Z block: o 0..255, k 0..255
        int o = i >> 8, k = i & 255;
        float v = (k < 128) ? Wih[o * 128 + k] : Whh[o * 128 + (k - 128)];
        Wpk[i] = f2h(v);
    } else if (i < 98304) {                // IN,HN block
        int j = i - 65536;
        int o = j >> 7, k = j & 127;       // o 0..255: 0..127 IN, 128..255 HN
        float v = (o < 128) ? Wih[(256 + o) * 128 + k] : Whh[(256 + (o - 128)) * 128 + k];
        Wpk[i] = f2h(v);
    }
    if (i < 512) {
        float b;
        if (i < 256) b = bih[i] + bhh[i];
        else if (i < 384) b = bih[i];
        else b = bhh[i - 128];
        bpk[i] = b;
    }
}

// ---------------- init h = [node_features | 0] (fp32 + fp16 shadow in hx) -------------
__global__ void k_init_h(const float* __restrict__ nf, float* __restrict__ h,
                         unsigned short* __restrict__ hx) {
    int i = blockIdx.x * 256 + threadIdx.x;
    if (i >= NN * OD) return;
    int n = i >> 7, d = i & 127;
    float v = (d < IND) ? nf[n * IND + d] : 0.f;
    h[i] = v;
    hx[(size_t)n * 256 + 128 + d] = f2h(v);
}

// ---------------- (dst, etype) CSR build: 200000 segments ----------------
__global__ void k_count(const int* __restrict__ dst, const int* __restrict__ et,
                        int* __restrict__ deg4) {
    int e = blockIdx.x * 256 + threadIdx.x;
    if (e < NE) atomicAdd(&deg4[dst[e] * 4 + et[e]], 1);
}

__global__ void k_scan1(const int* __restrict__ deg, int* __restrict__ rowp,
                        int* __restrict__ bsum, int n) {
    __shared__ int buf[1024];
    int tid = threadIdx.x;
    int i = blockIdx.x * 1024 + tid;
    int v = (i < n) ? deg[i] : 0;
    buf[tid] = v;
    __syncthreads();
    for (int off = 1; off < 1024; off <<= 1) {
        int t = (tid >= off) ? buf[tid - off] : 0;
        __syncthreads();
        buf[tid] += t;
        __syncthreads();
    }
    if (i < n) rowp[i + 1] = buf[tid];
    if (tid == 1023) bsum[blockIdx.x] = buf[tid];
}

__global__ void k_scan2(int* __restrict__ bsum, int nb) {
    __shared__ int buf[256];
    int tid = threadIdx.x;
    int v = (tid < nb) ? bsum[tid] : 0;
    buf[tid] = v;
    __syncthreads();
    for (int off = 1; off < 256; off <<= 1) {
        int t = (tid >= off) ? buf[tid - off] : 0;
        __syncthreads();
        buf[tid] += t;
        __syncthreads();
    }
    if (tid < nb) bsum[tid] = buf[tid] - v;   // exclusive
}

__global__ void k_scan3(const int* __restrict__ deg, const int* __restrict__ bsum,
                        int* __restrict__ rowp, int* __restrict__ cursor, int n) {
    int i = blockIdx.x * 256 + threadIdx.x;
    if (i >= n) return;
    int incl = rowp[i + 1] + bsum[i >> 10];
    rowp[i + 1] = incl;
    cursor[i] = incl - deg[i];
    if (i == 0) rowp[0] = 0;
}

__global__ void k_fill(const int* __restrict__ src, const int* __restrict__ dst,
                       const int* __restrict__ et, int* __restrict__ cursor,
                       int* __restrict__ epk) {
    int e = blockIdx.x * 256 + threadIdx.x;
    if (e < NE) {
        int t = et[e];
        int pos = atomicAdd(&cursor[dst[e] * 4 + t], 1);
        epk[pos] = src[e] | (t << 16);     // src < 2^16, et 2 bits
    }
}

// ---------------- graph CSR build (by graph id), for readout ----------------
__global__ void k_gcount(const int* __restrict__ gid, int* __restrict__ gdeg) {
    __shared__ int c[NG];
    int tid = threadIdx.x;
    if (tid < NG) c[tid] = 0;
    __syncthreads();
    int n = blockIdx.x * 1024 + tid;
    if (n < NN) atomicAdd(&c[gid[n]], 1);
    __syncthreads();
    if (tid < NG && c[tid] > 0) atomicAdd(&gdeg[tid], c[tid]);
}

__global__ void k_gscan(const int* __restrict__ gdeg, int* __restrict__ growp,
                        int* __restrict__ gcur) {
    __shared__ int buf[NG];
    int tid = threadIdx.x;
    int v = gdeg[tid];
    buf[tid] = v;
    __syncthreads();
    for (int off = 1; off < NG; off <<= 1) {
        int t = (tid >= off) ? buf[tid - off] : 0;
        __syncthreads();
        buf[tid] += t;
        __syncthreads();
    }
    growp[tid + 1] = buf[tid];
    gcur[tid] = buf[tid] - v;
    if (tid == 0) growp[0] = 0;
}

__global__ void k_gfill(const int* __restrict__ gid, int* __restrict__ gcur,
                        int* __restrict__ nlist) {
    __shared__ int lcnt[NG];
    __shared__ int lbase[NG];
    int tid = threadIdx.x;
    if (tid < NG) lcnt[tid] = 0;
    __syncthreads();
    int n = blockIdx.x * 1024 + tid;
    int g = -1, rank = 0;
    if (n < NN) { g = gid[n]; rank = atomicAdd(&lcnt[g], 1); }
    __syncthreads();
    if (tid < NG && lcnt[tid] > 0) lbase[tid] = atomicAdd(&gcur[tid], lcnt[tid]);
    __syncthreads();
    if (n < NN) nlist[lbase[g] + rank] = n;
}

// ---------------- fused aggregate + K=512 GEMM -> ab (hx cols 0..127) ----------------
// 1024 thr (16 waves), 32 dst rows/tile (grid 1563). Register gather:
// half-wave (32 lanes) per node, 4 dims/lane; 2-way unrolled edge loop, etype-
// predicated acc[4][4] f32. One barrier -> LDS s-tile [32][520] fp16 -> MFMA.
__global__ __launch_bounds__(1024) void k_agg_gemm(
    const unsigned short* __restrict__ hx,    // read cols 128..255 (hb)
    const int* __restrict__ rowp4, const int* __restrict__ epk,
    const int* __restrict__ deg4,
    const unsigned short* __restrict__ Wcat,  // 128 x 512 fp16 (out x [t|k])
    const float* __restrict__ bs,             // 4 * 128 fp32
    unsigned short* __restrict__ hxw) {       // write cols 0..127 (ab)
    __shared__ unsigned short Sh[32 * 520];   // 33.3 KB
    __shared__ float Bsb[512];

    const int tid = threadIdx.x;
    const int m0 = blockIdx.x * 32;

    if (tid < 512) Bsb[tid] = bs[tid];

    // ---- register gather ----
    const int r = tid >> 5;          // row 0..31
    const int l32 = tid & 31;        // dim group: dims l32*4..+4
    const int d0 = l32 * 4;
    const int n = m0 + r;

    float acc0[4], acc1[4], acc2[4], acc3[4];
#pragma unroll
    for (int k = 0; k < 4; ++k) { acc0[k] = 0.f; acc1[k] = 0.f; acc2[k] = 0.f; acc3[k] = 0.f; }

    if (n < NN) {
        int i = rowp4[n * 4], end = rowp4[n * 4 + 4];
        for (; i + 2 <= end; i += 2) {
            int p0 = epk[i], p1 = epk[i + 1];
            f16x4 v0 = *(const f16x4*)&hx[(size_t)(p0 & 0xFFFF) * 256 + 128 + d0];
            f16x4 v1 = *(const f16x4*)&hx[(size_t)(p1 & 0xFFFF) * 256 + 128 + d0];
            int e0 = p0 >> 16, e1 = p1 >> 16;
#pragma unroll
            for (int k = 0; k < 4; ++k) {
                float f0 = (float)v0[k], f1 = (float)v1[k];
                acc0[k] += (e0 == 0 ? f0 : 0.f) + (e1 == 0 ? f1 : 0.f);
                acc1[k] += (e0 == 1 ? f0 : 0.f) + (e1 == 1 ? f1 : 0.f);
                acc2[k] += (e0 == 2 ? f0 : 0.f) + (e1 == 2 ? f1 : 0.f);
                acc3[k] += (e0 == 3 ? f0 : 0.f) + (e1 == 3 ? f1 : 0.f);
            }
        }
        if (i < end) {
            int p0 = epk[i];
            f16x4 v0 = *(const f16x4*)&hx[(size_t)(p0 & 0xFFFF) * 256 + 128 + d0];
            int e0 = p0 >> 16;
#pragma unroll
            for (int k = 0; k < 4; ++k) {
                float f0 = (float)v0[k];
                acc0[k] += (e0 == 0 ? f0 : 0.f);
                acc1[k] += (e0 == 1 ? f0 : 0.f);
                acc2[k] += (e0 == 2 ? f0 : 0.f);
                acc3[k] += (e0 == 3 ? f0 : 0.f);
            }
        }
    }

    // s-tile to LDS fp16: row layout [t0 0..127 | t1 | t2 | t3], stride 520
    {
        f16x4 h0, h1, h2, h3;
#pragma unroll
        for (int k = 0; k < 4; ++k) {
            h0[k] = (_Float16)acc0[k]; h1[k] = (_Float16)acc1[k];
            h2[k] = (_Float16)acc2[k]; h3[k] = (_Float16)acc3[k];
        }
        unsigned short* sr = &Sh[r * 520];
        *(f16x4*)&sr[0 * 128 + d0] = h0;
        *(f16x4*)&sr[1 * 128 + d0] = h1;
        *(f16x4*)&sr[2 * 128 + d0] = h2;
        *(f16x4*)&sr[3 * 128 + d0] = h3;
    }
    __syncthreads();

    // ---- K=512 MFMA: wave w -> (rt = w&1, ct = w>>1), 1 f32x4 acc ----
    const int lane = tid & 63;
    const int w = tid >> 6;
    const int lr = lane & 15;
    const int q = lane >> 4;
    const int rt = w & 1;
    const int ct = w >> 1;

    f32x4 acc = (f32x4){0.f, 0.f, 0.f, 0.f};
#pragma unroll
    for (int ks = 0; ks < 16; ++ks) {
        f16x8 af = *(const f16x8*)&Sh[(rt * 16 + lr) * 520 + ks * 32 + q * 8];
        f16x8 bf = *(const f16x8*)&Wcat[(ct * 16 + lr) * 512 + ks * 32 + q * 8];
        acc = __builtin_amdgcn_mfma_f32_16x16x32_f16(af, bf, acc, 0, 0, 0);
    }

    // epilogue: + sum_t cnt*bs, fp16 store into ab half
    int rowbase = m0 + rt * 16 + q * 4;
#pragma unroll
    for (int rr = 0; rr < 4; ++rr) {
        int n2 = rowbase + rr;
        if (n2 < NN) {
            int4 c = *(const int4*)&deg4[n2 * 4];
            int col = ct * 16 + lr;
            float v = acc[rr]
                    + c.x * Bsb[col] + c.y * Bsb[128 + col]
                    + c.z * Bsb[256 + col] + c.w * Bsb[384 + col];
            hxw[(size_t)n2 * 256 + col] = f2h(v);
        }
    }
}

// ---------------- fused gates GEMM + GRU (1024 thr, 64 rows, ~72KB LDS) --------------
// Wave (rg = w>>2 -> 0..3, g = w&3): gate g for rows rg*16..+16, acc[8] (32 VGPR).
// g=0:R (K=256), 1:Z (K=256), 2:IN (K=128, ab), 3:HN (K=128, hb).
// Gates -> LDS fp16 (R,Z post-sigmoid; IN,HN pre-tanh, biases folded), then GRU
// pointwise (8 elems/thread), write h fp32 + hb half of hx.
__global__ __launch_bounds__(1024) void k_gates_gru(
    const unsigned short* __restrict__ hx,
    const unsigned short* __restrict__ Wpk,   // packed: R|Z (256-K) then IN|HN (128-K)
    const float* __restrict__ bpk,            // 512 packed biases
    float* __restrict__ h,
    unsigned short* __restrict__ hxw) {
    // phase 1: As[2][64][136] (17408 halfs); phase 2: G[4][64][136] (34816 halfs)
    __shared__ unsigned short LS[4 * 64 * 136];   // 69632 B
    __shared__ float Bsb[512];

    const int tid = threadIdx.x;
    const int m0 = blockIdx.x * 64;

    if (tid < 512) Bsb[tid] = bpk[tid];

    const uint4* H4 = (const uint4*)hx;   // 32 uint4 per 256-half row
#pragma unroll
    for (int it = 0; it < 2; ++it) {
        int i = tid + it * 1024;          // 0..2047
        int row = i >> 5, qq = i & 31;
        int nn = m0 + row;
        uint4 v = (nn < NN) ? H4[(size_t)nn * 32 + qq] : make_uint4(0u, 0u, 0u, 0u);
        *(uint4*)&LS[(qq >> 4) * 8704 + row * 136 + (qq & 15) * 8] = v;
    }
    __syncthreads();

    const int lane = tid & 63;
    const int w = tid >> 6;
    const int lr = lane & 15;
    const int q = lane >> 4;
    const int rg = w >> 2;       // row-group 0..3 (16 rows)
    const int g = w & 3;         // gate: 0=R 1=Z 2=IN 3=HN

    f32x4 acc[8];
#pragma unroll
    for (int nt = 0; nt < 8; ++nt) acc[nt] = (f32x4){0.f, 0.f, 0.f, 0.f};

    if (g < 2) {   // R / Z: K=256 over [ab|hb]
        const unsigned short* Wg = Wpk + g * 32768;
#pragma unroll
        for (int ks = 0; ks < 8; ++ks) {
            int chunk = ks >> 2, ksl = ks & 3;
            f16x8 af = *(const f16x8*)&LS[chunk * 8704
                       + (rg * 16 + lr) * 136 + ksl * 32 + q * 8];
#pragma unroll
            for (int nt = 0; nt < 8; ++nt) {
                f16x8 bf = *(const f16x8*)&Wg[(nt * 16 + lr) * 256 + ks * 32 + q * 8];
                acc[nt] = __builtin_amdgcn_mfma_f32_16x16x32_f16(af, bf, acc[nt], 0, 0, 0);
            }
        }
    } else {       // IN (chunk 0 = ab) / HN (chunk 1 = hb): K=128
        const int chunk = g - 2;
        const unsigned short* Wg = Wpk + 65536 + chunk * 16384;
#pragma unroll
        for (int ks = 0; ks < 4; ++ks) {
            f16x8 af = *(const f16x8*)&LS[chunk * 8704
                       + (rg * 16 + lr) * 136 + ks * 32 + q * 8];
#pragma unroll
            for (int nt = 0; nt < 8; ++nt) {
                f16x8 bf = *(const f16x8*)&Wg[(nt * 16 + lr) * 128 + ks * 32 + q * 8];
                acc[nt] = __builtin_amdgcn_mfma_f32_16x16x32_f16(af, bf, acc[nt], 0, 0, 0);
            }
        }
    }
    __syncthreads();   // all MFMA done; As region dead, reuse LS for gates

    // store gate tile to LDS (fp16), bias folded; sigmoid for R/Z
    {
        const int gb = g * 8704;
        const int bofs = g * 128;
        int rowb = rg * 16 + q * 4;
#pragma unroll
        for (int rr = 0; rr < 4; ++rr) {
            int row = rowb + rr;
#pragma unroll
            for (int nt = 0; nt < 8; ++nt) {
                int col = nt * 16 + lr;
                float v = acc[nt][rr] + Bsb[bofs + col];
                if (g < 2) v = 1.f / (1.f + __expf(-v));
                LS[gb + row * 136 + col] = f2h(v);
            }
        }
    }
    __syncthreads();

    // GRU pointwise: thread -> (row = tid>>4, cols (tid&15)*8 .. +8)
    {
        int row = tid >> 4;          // 0..63
        int c = (tid & 15) * 8;
        int n2 = m0 + row;
        if (n2 < NN) {
            float* hrow = h + (size_t)n2 * OD;
            unsigned short* hbrow = hxw + (size_t)n2 * 256 + 128;
            const int rb = row * 136 + c;
            f16x8 Rv = *(const f16x8*)&LS[rb];
            f16x8 Zv = *(const f16x8*)&LS[8704 + rb];
            f16x8 Iv = *(const f16x8*)&LS[17408 + rb];
            f16x8 Hv = *(const f16x8*)&LS[26112 + rb];
            float4 h0 = *(const float4*)&hrow[c];
            float4 h1 = *(const float4*)&hrow[c + 4];
            float hold[8] = {h0.x, h0.y, h0.z, h0.w, h1.x, h1.y, h1.z, h1.w};
            float hn8[8];
            f16x8 hb8;
#pragma unroll
            for (int k = 0; k < 8; ++k) {
                float R = (float)Rv[k], Z = (float)Zv[k];
                float NV = tanhf((float)Iv[k] + R * (float)Hv[k]);
                float v = (1.f - Z) * NV + Z * hold[k];
                hn8[k] = v;
                hb8[k] = (_Float16)v;
            }
            *(float4*)&hrow[c]     = make_float4(hn8[0], hn8[1], hn8[2], hn8[3]);
            *(float4*)&hrow[c + 4] = make_float4(hn8[4], hn8[5], hn8[6], hn8[7]);
            *(f16x8*)&hbrow[c] = hb8;
        }
    }
}

// ---------------- graph readout: register acc over graph-sorted node list ------------
__global__ void k_readout(const float* __restrict__ h, const float* __restrict__ nf,
                          const int* __restrict__ nlist, const int* __restrict__ growp,
                          float* __restrict__ partial) {
    int g = blockIdx.x >> 3, c = blockIdx.x & (RC - 1);
    int d = threadIdx.x;
    int s = growp[g], e = growp[g + 1], len = e - s;
    int i0 = s + (int)((long long)len * c / RC);
    int i1 = s + (int)((long long)len * (c + 1) / RC);
    float acc = 0.f;
    for (int i = i0; i < i1; ++i) {
        int n = nlist[i];
        acc += (d < OD) ? h[(size_t)n * OD + d] : nf[(size_t)n * IND + (d - OD)];
    }
    partial[(size_t)blockIdx.x * 192 + d] = acc;
}

__global__ void k_reduce(const float* __restrict__ partial, float* __restrict__ feats) {
    int i = blockIdx.x * 256 + threadIdx.x;
    if (i >= NG * 192) return;
    int g = i / 192, d = i % 192;
    float s = 0.f;
    for (int c = 0; c < RC; ++c) s += partial[(size_t)(g * RC + c) * 192 + d];
    feats[i] = s;
}

__global__ void k_final(const float* __restrict__ feats, const float* __restrict__ W_cls,
                        const float* __restrict__ b_cls, float* __restrict__ out) {
    int g = threadIdx.x;
    if (g >= NG) return;
    float acc = b_cls[0];
    for (int d = 0; d < 192; ++d) acc += feats[g * 192 + d] * W_cls[d];
    out[g] = 1.f / (1.f + __expf(-acc));
}

extern "C" void kernel_launch(void* const* d_in, const int* in_sizes, int n_in,
                              void* d_out, int out_size, void* d_ws, size_t ws_size,
                              hipStream_t stream) {
    const float* nf    = (const float*)d_in[0];
    const int*   src   = (const int*)d_in[1];
    const int*   dst   = (const int*)d_in[2];
    const int*   et    = (const int*)d_in[3];
    const int*   gid   = (const int*)d_in[4];
    const float* Ws    = (const float*)d_in[5];
    const float* bs    = (const float*)d_in[6];
    const float* W_ih  = (const float*)d_in[7];
    const float* W_hh  = (const float*)d_in[8];
    const float* b_ih  = (const float*)d_in[9];
    const float* b_hh  = (const float*)d_in[10];
    const float* W_cls = (const float*)d_in[11];
    const float* b_cls = (const float*)d_in[12];
    float* out = (float*)d_out;

    char* ws = (char*)d_ws;
    size_t off = 0;
    auto alloc = [&](size_t bytes) -> void* {
        off = (off + 255) & ~(size_t)255;
        void* p = ws + off;
        off += bytes;
        return p;
    };
    float*          h    = (float*)alloc((size_t)NN * OD * 4);              // 25.6 MB
    unsigned short* hx   = (unsigned short*)alloc((size_t)NN * 256 * 2);    // 25.6 MB
    int*   deg4    = (int*)alloc((size_t)NN4 * 4);
    int*   rowp4   = (int*)alloc((size_t)(NN4 + 1) * 4);
    int*   cursor4 = (int*)alloc((size_t)NN4 * 4);
    int*   epk     = (int*)alloc((size_t)NE * 4);
    int*   bsum    = (int*)alloc(256 * 4);
    int*   gdeg    = (int*)alloc(NG * 4);
    int*   growp   = (int*)alloc((NG + 1) * 4);
    int*   gcur    = (int*)alloc(NG * 4);
    int*   nlist   = (int*)alloc((size_t)NN * 4);
    float* feats   = (float*)alloc((size_t)NG * 192 * 4);
    float* partial = (float*)alloc((size_t)NG * RC * 192 * 4);              // 393 KB
    unsigned short* Wcat = (unsigned short*)alloc((size_t)65536 * 2);       // 128 KB
    unsigned short* Wpk  = (unsigned short*)alloc((size_t)98304 * 2);
    float*          bpk  = (float*)alloc(512 * 4);
    (void)ws_size; (void)in_sizes; (void)n_in; (void)out_size;

    hipMemsetAsync(deg4, 0, (size_t)NN4 * 4, stream);
    hipMemsetAsync(gdeg, 0, NG * 4, stream);

    k_cvtws<<<(65536 + 255) / 256, 256, 0, stream>>>(Ws, Wcat);
    k_pack<<<(98304 + 255) / 256, 256, 0, stream>>>(W_ih, W_hh, b_ih, b_hh, Wpk, bpk);

    k_init_h<<<(NN * OD + 255) / 256, 256, 0, stream>>>(nf, h, hx);

    // (dst, etype) CSR
    k_count<<<(NE + 255) / 256, 256, 0, stream>>>(dst, et, deg4);
    const int nb4 = (NN4 + 1023) / 1024;   // 196
    k_scan1<<<nb4, 1024, 0, stream>>>(deg4, rowp4, bsum, NN4);
    k_scan2<<<1, 256, 0, stream>>>(bsum, nb4);
    k_scan3<<<(NN4 + 255) / 256, 256, 0, stream>>>(deg4, bsum, rowp4, cursor4, NN4);
    k_fill<<<(NE + 255) / 256, 256, 0, stream>>>(src, dst, et, cursor4, epk);

    // graph CSR (readout)
    const int nbn = (NN + 1023) / 1024;    // 49
    k_gcount<<<nbn, 1024, 0, stream>>>(gid, gdeg);
    k_gscan<<<1, NG, 0, stream>>>(gdeg, growp, gcur);
    k_gfill<<<nbn, 1024, 0, stream>>>(gid, gcur, nlist);

    const int mt32 = (NN + 31) / 32;   // 1563 node tiles
    const int mt64 = (NN + 63) / 64;   // 782 node tiles
    for (int s = 0; s < 8; ++s) {
        k_agg_gemm<<<mt32, 1024, 0, stream>>>(hx, rowp4, epk, deg4, Wcat, bs, hx);
        k_gates_gru<<<mt64, 1024, 0, stream>>>(hx, Wpk, bpk, h, hx);
    }

    k_readout<<<NG * RC, 192, 0, stream>>>(h, nf, nlist, growp, partial);
    k_reduce<<<(NG * 192 + 255) / 256, 256, 0, stream>>>(partial, feats);
    k_final<<<1, 64, 0, stream>>>(feats, W_cls, b_cls, out);
}

// Round 6
// 1132.580 us; speedup vs baseline: 3.1773x; 1.5704x over previous
//
#include <hip/hip_runtime.h>
#include <hip/hip_bf16.h>
#include <math.h>

// GGNN: N=50000 nodes, E=400000 edges, G=64 graphs, IN=64, OUT=128, 4 etypes, 8 steps.
// R11: LDS-staged weights for gates (B-from-global was the 3x latency killer in
//      R7/R8/R10); flat predicated register gather for aggregation.
//   hx[N][256] fp16: cols 0..127 = ab (aggregated msg), cols 128..255 = hb (h shadow).
//   k_agg_gemm (256 thr, 32 rows): 8 thr/row (16 dims), ONE flat walk over the node's
//     contiguous (dst,et)-sorted edge range, 2-way unroll, etype-predicated acc[4][16]
//     (static indices). Per-etype s-planes in LDS -> K=512 MFMA (Wcat from L2),
//     + cnt*bs epilogue -> ab half of hx.
//   k_gates_gru (512 thr, 64 rows, 70.7KB LDS -> 2 blk/CU): A-tile (full hx row,
//     K=256) staged once; 6 weight chunks (R_ih,R_hh,Z_ih,Z_hh,IN_ih,HN_hh; 128x128
//     each) staged to LDS sequentially; MFMA loop pure-LDS. Each wave owns 4 output
//     tiles and accumulates ALL gates for them (accR/Z/I/H[4] f32x4) -> GRU entirely
//     in-register -> h fp32 + hb half. No O/G table.

#define NN 50000
#define NE 400000
#define NG 64
#define IND 64
#define OD 128
#define NN4 (NN * 4)
#define RC 8      // readout chunks per graph

typedef _Float16 f16x8 __attribute__((ext_vector_type(8)));
typedef _Float16 f16x4 __attribute__((ext_vector_type(4)));
typedef _Float16 f16x2 __attribute__((ext_vector_type(2)));
typedef float f32x4 __attribute__((ext_vector_type(4)));

__device__ inline unsigned short f2h(float x) {
    _Float16 hv = (_Float16)x;
    unsigned short u;
    __builtin_memcpy(&u, &hv, 2);
    return u;
}

// ---------------- Ws fp32 -> concatenated fp16 Wcat[o][t*128+k] ----------------
__global__ void k_cvtws(const float* __restrict__ Ws, unsigned short* __restrict__ Wcat) {
    int i = blockIdx.x * 256 + threadIdx.x;   // 65536
    if (i >= 65536) return;
    int o = i >> 9, col = i & 511;
    int t = col >> 7, k = col & 127;
    Wcat[i] = f2h(Ws[t * 16384 + o * 128 + k]);
}

// ---------------- pack GRU weights into 6 stage-chunks of 128x128 fp16 ----------------
// chunk c: rows (c>>1)*128..+128 of (c&1 ? W_hh : W_ih)
//   c0=R_ih c1=R_hh c2=Z_ih c3=Z_hh c4=IN_ih c5=HN_hh
// bpk[0..255] = b_ih+b_hh (r,z), bpk[256..383] = b_ih[256..], bpk[384..511] = b_hh[256..]
__global__ void k_pack(const float* __restrict__ Wih, const float* __restrict__ Whh,
                       const float* __restrict__ bih, const float* __restrict__ bhh,
                       unsigned short* __restrict__ Wpk, float* __restrict__ bpk) {
    int i = blockIdx.x * 256 + threadIdx.x;
    if (i < 98304) {
        int c = i >> 14, j = i & 16383, o = j >> 7, k = j & 127;
        const float* W = (c & 1) ? Whh : Wih;
        Wpk[i] = f2h(W[((c >> 1) * 128 + o) * 128 + k]);
    }
    if (i < 512) {
        float b;
        if (i < 256) b = bih[i] + bhh[i];
        else if (i < 384) b = bih[i];
        else b = bhh[i - 128];
        bpk[i] = b;
    }
}

// ---------------- init h = [node_features | 0] (fp32 + fp16 shadow in hx) -------------
__global__ void k_init_h(const float* __restrict__ nf, float* __restrict__ h,
                         unsigned short* __restrict__ hx) {
    int i = blockIdx.x * 256 + threadIdx.x;
    if (i >= NN * OD) return;
    int n = i >> 7, d = i & 127;
    float v = (d < IND) ? nf[n * IND + d] : 0.f;
    h[i] = v;
    hx[(size_t)n * 256 + 128 + d] = f2h(v);
}

// ---------------- (dst, etype) CSR build: 200000 segments ----------------
__global__ void k_count(const int* __restrict__ dst, const int* __restrict__ et,
                        int* __restrict__ deg4) {
    int e = blockIdx.x * 256 + threadIdx.x;
    if (e < NE) atomicAdd(&deg4[dst[e] * 4 + et[e]], 1);
}

__global__ void k_scan1(const int* __restrict__ deg, int* __restrict__ rowp,
                        int* __restrict__ bsum, int n) {
    __shared__ int buf[1024];
    int tid = threadIdx.x;
    int i = blockIdx.x * 1024 + tid;
    int v = (i < n) ? deg[i] : 0;
    buf[tid] = v;
    __syncthreads();
    for (int off = 1; off < 1024; off <<= 1) {
        int t = (tid >= off) ? buf[tid - off] : 0;
        __syncthreads();
        buf[tid] += t;
        __syncthreads();
    }
    if (i < n) rowp[i + 1] = buf[tid];
    if (tid == 1023) bsum[blockIdx.x] = buf[tid];
}

__global__ void k_scan2(int* __restrict__ bsum, int nb) {
    __shared__ int buf[256];
    int tid = threadIdx.x;
    int v = (tid < nb) ? bsum[tid] : 0;
    buf[tid] = v;
    __syncthreads();
    for (int off = 1; off < 256; off <<= 1) {
        int t = (tid >= off) ? buf[tid - off] : 0;
        __syncthreads();
        buf[tid] += t;
        __syncthreads();
    }
    if (tid < nb) bsum[tid] = buf[tid] - v;   // exclusive
}

__global__ void k_scan3(const int* __restrict__ deg, const int* __restrict__ bsum,
                        int* __restrict__ rowp, int* __restrict__ cursor, int n) {
    int i = blockIdx.x * 256 + threadIdx.x;
    if (i >= n) return;
    int incl = rowp[i + 1] + bsum[i >> 10];
    rowp[i + 1] = incl;
    cursor[i] = incl - deg[i];
    if (i == 0) rowp[0] = 0;
}

__global__ void k_fill(const int* __restrict__ src, const int* __restrict__ dst,
                       const int* __restrict__ et, int* __restrict__ cursor,
                       int* __restrict__ epk) {
    int e = blockIdx.x * 256 + threadIdx.x;
    if (e < NE) {
        int t = et[e];
        int pos = atomicAdd(&cursor[dst[e] * 4 + t], 1);
        epk[pos] = src[e] | (t << 16);     // src < 2^16, et 2 bits
    }
}

// ---------------- graph CSR build (by graph id), for readout ----------------
__global__ void k_gcount(const int* __restrict__ gid, int* __restrict__ gdeg) {
    __shared__ int c[NG];
    int tid = threadIdx.x;
    if (tid < NG) c[tid] = 0;
    __syncthreads();
    int n = blockIdx.x * 1024 + tid;
    if (n < NN) atomicAdd(&c[gid[n]], 1);
    __syncthreads();
    if (tid < NG && c[tid] > 0) atomicAdd(&gdeg[tid], c[tid]);
}

__global__ void k_gscan(const int* __restrict__ gdeg, int* __restrict__ growp,
                        int* __restrict__ gcur) {
    __shared__ int buf[NG];
    int tid = threadIdx.x;
    int v = gdeg[tid];
    buf[tid] = v;
    __syncthreads();
    for (int off = 1; off < NG; off <<= 1) {
        int t = (tid >= off) ? buf[tid - off] : 0;
        __syncthreads();
        buf[tid] += t;
        __syncthreads();
    }
    growp[tid + 1] = buf[tid];
    gcur[tid] = buf[tid] - v;
    if (tid == 0) growp[0] = 0;
}

__global__ void k_gfill(const int* __restrict__ gid, int* __restrict__ gcur,
                        int* __restrict__ nlist) {
    __shared__ int lcnt[NG];
    __shared__ int lbase[NG];
    int tid = threadIdx.x;
    if (tid < NG) lcnt[tid] = 0;
    __syncthreads();
    int n = blockIdx.x * 1024 + tid;
    int g = -1, rank = 0;
    if (n < NN) { g = gid[n]; rank = atomicAdd(&lcnt[g], 1); }
    __syncthreads();
    if (tid < NG && lcnt[tid] > 0) lbase[tid] = atomicAdd(&gcur[tid], lcnt[tid]);
    __syncthreads();
    if (n < NN) nlist[lbase[g] + rank] = n;
}

// ---------------- fused aggregate + K=512 GEMM -> ab (hx cols 0..127) ----------------
// 256 thr (4 waves), 32 rows/tile (grid 1563). 8 thr/row (16 dims each).
// Flat walk over the node's contiguous edge range, 2-way unroll, predicated acc[4][16].
// s-planes [t][32][136] fp16 in LDS -> MFMA (Wcat from L2), + cnt*bs -> ab half.
__global__ __launch_bounds__(256) void k_agg_gemm(
    const unsigned short* __restrict__ hx,    // read cols 128..255 (hb)
    const int* __restrict__ rowp4, const int* __restrict__ epk,
    const int* __restrict__ deg4,
    const unsigned short* __restrict__ Wcat,  // 128 x 512 fp16 (out x [t|k])
    const float* __restrict__ bs,             // 4 * 128 fp32
    unsigned short* __restrict__ hxw) {       // write cols 0..127 (ab)
    __shared__ unsigned short Sh[4 * 32 * 136];   // 34.8 KB: plane t, row, col
    __shared__ float Bsb[512];

    const int tid = threadIdx.x;
    const int m0 = blockIdx.x * 32;

    Bsb[tid] = bs[tid];
    Bsb[tid + 256] = bs[tid + 256];

    const int r = tid >> 3;          // row 0..31
    const int sl = tid & 7;          // 16-dim slice
    const int d0 = sl * 16;
    const int n = m0 + r;

    float a0[16], a1[16], a2[16], a3[16];
#pragma unroll
    for (int k = 0; k < 16; ++k) { a0[k] = 0.f; a1[k] = 0.f; a2[k] = 0.f; a3[k] = 0.f; }

    if (n < NN) {
        int i = rowp4[n * 4], end = rowp4[n * 4 + 4];
        for (; i + 2 <= end; i += 2) {
            int p0 = epk[i], p1 = epk[i + 1];
            const f16x8* r0 = (const f16x8*)&hx[(size_t)(p0 & 0xFFFF) * 256 + 128 + d0];
            const f16x8* r1 = (const f16x8*)&hx[(size_t)(p1 & 0xFFFF) * 256 + 128 + d0];
            f16x8 u0 = r0[0], u1 = r0[1];
            f16x8 v0 = r1[0], v1 = r1[1];
            int e0 = p0 >> 16, e1 = p1 >> 16;
#pragma unroll
            for (int k = 0; k < 8; ++k) {
                float f0 = (float)u0[k], f1 = (float)u1[k];
                float g0 = (float)v0[k], g1 = (float)v1[k];
                a0[k]     += (e0 == 0 ? f0 : 0.f) + (e1 == 0 ? g0 : 0.f);
                a0[8 + k] += (e0 == 0 ? f1 : 0.f) + (e1 == 0 ? g1 : 0.f);
                a1[k]     += (e0 == 1 ? f0 : 0.f) + (e1 == 1 ? g0 : 0.f);
                a1[8 + k] += (e0 == 1 ? f1 : 0.f) + (e1 == 1 ? g1 : 0.f);
                a2[k]     += (e0 == 2 ? f0 : 0.f) + (e1 == 2 ? g0 : 0.f);
                a2[8 + k] += (e0 == 2 ? f1 : 0.f) + (e1 == 2 ? g1 : 0.f);
                a3[k]     += (e0 == 3 ? f0 : 0.f) + (e1 == 3 ? g0 : 0.f);
                a3[8 + k] += (e0 == 3 ? f1 : 0.f) + (e1 == 3 ? g1 : 0.f);
            }
        }
        if (i < end) {
            int p0 = epk[i];
            const f16x8* r0 = (const f16x8*)&hx[(size_t)(p0 & 0xFFFF) * 256 + 128 + d0];
            f16x8 u0 = r0[0], u1 = r0[1];
            int e0 = p0 >> 16;
#pragma unroll
            for (int k = 0; k < 8; ++k) {
                float f0 = (float)u0[k], f1 = (float)u1[k];
                a0[k] += (e0 == 0 ? f0 : 0.f); a0[8 + k] += (e0 == 0 ? f1 : 0.f);
                a1[k] += (e0 == 1 ? f0 : 0.f); a1[8 + k] += (e0 == 1 ? f1 : 0.f);
                a2[k] += (e0 == 2 ? f0 : 0.f); a2[8 + k] += (e0 == 2 ? f1 : 0.f);
                a3[k] += (e0 == 3 ? f0 : 0.f); a3[8 + k] += (e0 == 3 ? f1 : 0.f);
            }
        }
    }

    // write per-etype planes
    {
        f16x8 w0, w1;
#pragma unroll
        for (int k = 0; k < 8; ++k) { w0[k] = (_Float16)a0[k]; w1[k] = (_Float16)a0[8 + k]; }
        *(f16x8*)&Sh[0 * 4352 + r * 136 + d0] = w0; *(f16x8*)&Sh[0 * 4352 + r * 136 + d0 + 8] = w1;
#pragma unroll
        for (int k = 0; k < 8; ++k) { w0[k] = (_Float16)a1[k]; w1[k] = (_Float16)a1[8 + k]; }
        *(f16x8*)&Sh[1 * 4352 + r * 136 + d0] = w0; *(f16x8*)&Sh[1 * 4352 + r * 136 + d0 + 8] = w1;
#pragma unroll
        for (int k = 0; k < 8; ++k) { w0[k] = (_Float16)a2[k]; w1[k] = (_Float16)a2[8 + k]; }
        *(f16x8*)&Sh[2 * 4352 + r * 136 + d0] = w0; *(f16x8*)&Sh[2 * 4352 + r * 136 + d0 + 8] = w1;
#pragma unroll
        for (int k = 0; k < 8; ++k) { w0[k] = (_Float16)a3[k]; w1[k] = (_Float16)a3[8 + k]; }
        *(f16x8*)&Sh[3 * 4352 + r * 136 + d0] = w0; *(f16x8*)&Sh[3 * 4352 + r * 136 + d0 + 8] = w1;
    }
    __syncthreads();

    // K=512 MFMA: wave w -> rt = w>>1 (16 rows), col-tiles cts..cts+3
    const int lane = tid & 63;
    const int w = tid >> 6;
    const int lr = lane & 15;
    const int q = lane >> 4;
    const int rt = w >> 1;
    const int cts = (w & 1) * 4;

    f32x4 acc[4];
#pragma unroll
    for (int j = 0; j < 4; ++j) acc[j] = (f32x4){0.f, 0.f, 0.f, 0.f};

#pragma unroll
    for (int ks = 0; ks < 16; ++ks) {
        int t = ks >> 2, ksl = ks & 3;
        f16x8 af = *(const f16x8*)&Sh[t * 4352 + (rt * 16 + lr) * 136 + ksl * 32 + q * 8];
#pragma unroll
        for (int j = 0; j < 4; ++j) {
            f16x8 bf = *(const f16x8*)&Wcat[((cts + j) * 16 + lr) * 512 + ks * 32 + q * 8];
            acc[j] = __builtin_amdgcn_mfma_f32_16x16x32_f16(af, bf, acc[j], 0, 0, 0);
        }
    }

    // epilogue: + sum_t cnt*bs, fp16 store into ab half
    int rowbase = m0 + rt * 16 + q * 4;
#pragma unroll
    for (int rr = 0; rr < 4; ++rr) {
        int n2 = rowbase + rr;
        if (n2 < NN) {
            int4 c = *(const int4*)&deg4[n2 * 4];
            unsigned short* arow = hxw + (size_t)n2 * 256;
#pragma unroll
            for (int j = 0; j < 4; ++j) {
                int col = (cts + j) * 16 + lr;
                float v = acc[j][rr]
                        + c.x * Bsb[col] + c.y * Bsb[128 + col]
                        + c.z * Bsb[256 + col] + c.w * Bsb[384 + col];
                arow[col] = f2h(v);
            }
        }
    }
}

// ---------------- fused gates GEMM + GRU (512 thr, 64 rows, 70.7KB LDS) --------------
// A-tile = hx rows (K=256) staged once. 6 weight chunks (128x128) staged to LDS
// sequentially; MFMA pure-LDS. Wave w owns tiles (rt=w>>1, ct=(w&1)*4+j): accumulates
// R,Z,IN,HN for those tiles -> GRU in-register -> h fp32 + hb half of hx.
__global__ __launch_bounds__(512) void k_gates_gru(
    const unsigned short* __restrict__ hx,
    const unsigned short* __restrict__ Wpk,   // 6 chunks of 128x128 fp16
    const float* __restrict__ bpk,            // 512 packed biases
    float* __restrict__ h,
    unsigned short* __restrict__ hxw) {
    __shared__ unsigned short As[64 * 264];   // 33.8 KB (full 256-col rows, pad 8)
    __shared__ unsigned short Bs[128 * 136];  // 34.8 KB (one weight chunk)
    __shared__ float Bsb[512];

    const int tid = threadIdx.x;
    const int m0 = blockIdx.x * 64;

    Bsb[tid] = bpk[tid];   // 512 threads

    const uint4* H4 = (const uint4*)hx;   // 32 uint4 per 256-half row
#pragma unroll
    for (int it = 0; it < 4; ++it) {
        int i = tid + it * 512;           // 0..2047
        int row = i >> 5, qq = i & 31;
        int nn = m0 + row;
        uint4 v = (nn < NN) ? H4[(size_t)nn * 32 + qq] : make_uint4(0u, 0u, 0u, 0u);
        *(uint4*)&As[row * 264 + qq * 8] = v;
    }

    const int lane = tid & 63;
    const int w = tid >> 6;
    const int lr = lane & 15;
    const int q = lane >> 4;
    const int rt = w >> 1;        // row-tile 0..3
    const int cts = (w & 1) * 4;  // col-tile base

    const uint4* W4 = (const uint4*)Wpk;

    f32x4 accR[4], accZ[4], accI[4], accH[4];
#pragma unroll
    for (int j = 0; j < 4; ++j) {
        accR[j] = (f32x4){0.f, 0.f, 0.f, 0.f};
        accZ[j] = (f32x4){0.f, 0.f, 0.f, 0.f};
        accI[j] = (f32x4){0.f, 0.f, 0.f, 0.f};
        accH[j] = (f32x4){0.f, 0.f, 0.f, 0.f};
    }

#define GCHUNK(C, ACC)                                                              \
    __syncthreads();                                                                \
    _Pragma("unroll")                                                               \
    for (int it = 0; it < 4; ++it) {                                                \
        int i = tid + it * 512;                                                     \
        *(uint4*)&Bs[(i >> 4) * 136 + (i & 15) * 8] = W4[(C) * 2048 + i];           \
    }                                                                               \
    __syncthreads();                                                                \
    _Pragma("unroll")                                                               \
    for (int ks = 0; ks < 4; ++ks) {                                                \
        f16x8 af = *(const f16x8*)&As[(rt * 16 + lr) * 264 + ((C) & 1) * 128        \
                                      + ks * 32 + q * 8];                           \
        _Pragma("unroll")                                                           \
        for (int j = 0; j < 4; ++j) {                                               \
            f16x8 bf = *(const f16x8*)&Bs[((cts + j) * 16 + lr) * 136               \
                                          + ks * 32 + q * 8];                       \
            ACC[j] = __builtin_amdgcn_mfma_f32_16x16x32_f16(af, bf, ACC[j], 0, 0, 0); \
        }                                                                           \
    }

    GCHUNK(0, accR)   // R  += ab . W_ih_r
    GCHUNK(1, accR)   // R  += hb . W_hh_r
    GCHUNK(2, accZ)   // Z  += ab . W_ih_z
    GCHUNK(3, accZ)   // Z  += hb . W_hh_z
    GCHUNK(4, accI)   // IN  = ab . W_ih_n
    GCHUNK(5, accH)   // HN  = hb . W_hh_n
#undef GCHUNK

    // GRU in-register
    int rowb = m0 + rt * 16 + q * 4;
#pragma unroll
    for (int rr = 0; rr < 4; ++rr) {
        int n2 = rowb + rr;
        if (n2 < NN) {
            float* hrow = h + (size_t)n2 * OD;
            unsigned short* hbrow = hxw + (size_t)n2 * 256 + 128;
#pragma unroll
            for (int j = 0; j < 4; ++j) {
                int col = (cts + j) * 16 + lr;
                float R = 1.f / (1.f + __expf(-(accR[j][rr] + Bsb[col])));
                float Z = 1.f / (1.f + __expf(-(accZ[j][rr] + Bsb[128 + col])));
                float NV = tanhf(accI[j][rr] + Bsb[256 + col]
                                 + R * (accH[j][rr] + Bsb[384 + col]));
                float hold = hrow[col];
                float hnew = (1.f - Z) * NV + Z * hold;
                hrow[col] = hnew;
                hbrow[col] = f2h(hnew);
            }
        }
    }
}

// ---------------- graph readout: register acc over graph-sorted node list ------------
__global__ void k_readout(const float* __restrict__ h, const float* __restrict__ nf,
                          const int* __restrict__ nlist, const int* __restrict__ growp,
                          float* __restrict__ partial) {
    int g = blockIdx.x >> 3, c = blockIdx.x & (RC - 1);
    int d = threadIdx.x;
    int s = growp[g], e = growp[g + 1], len = e - s;
    int i0 = s + (int)((long long)len * c / RC);
    int i1 = s + (int)((long long)len * (c + 1) / RC);
    float acc = 0.f;
    for (int i = i0; i < i1; ++i) {
        int n = nlist[i];
        acc += (d < OD) ? h[(size_t)n * OD + d] : nf[(size_t)n * IND + (d - OD)];
    }
    partial[(size_t)blockIdx.x * 192 + d] = acc;
}

__global__ void k_reduce(const float* __restrict__ partial, float* __restrict__ feats) {
    int i = blockIdx.x * 256 + threadIdx.x;
    if (i >= NG * 192) return;
    int g = i / 192, d = i % 192;
    float s = 0.f;
    for (int c = 0; c < RC; ++c) s += partial[(size_t)(g * RC + c) * 192 + d];
    feats[i] = s;
}

__global__ void k_final(const float* __restrict__ feats, const float* __restrict__ W_cls,
                        const float* __restrict__ b_cls, float* __restrict__ out) {
    int g = threadIdx.x;
    if (g >= NG) return;
    float acc = b_cls[0];
    for (int d = 0; d < 192; ++d) acc += feats[g * 192 + d] * W_cls[d];
    out[g] = 1.f / (1.f + __expf(-acc));
}

extern "C" void kernel_launch(void* const* d_in, const int* in_sizes, int n_in,
                              void* d_out, int out_size, void* d_ws, size_t ws_size,
                              hipStream_t stream) {
    const float* nf    = (const float*)d_in[0];
    const int*   src   = (const int*)d_in[1];
    const int*   dst   = (const int*)d_in[2];
    const int*   et    = (const int*)d_in[3];
    const int*   gid   = (const int*)d_in[4];
    const float* Ws    = (const float*)d_in[5];
    const float* bs    = (const float*)d_in[6];
    const float* W_ih  = (const float*)d_in[7];
    const float* W_hh  = (const float*)d_in[8];
    const float* b_ih  = (const float*)d_in[9];
    const float* b_hh  = (const float*)d_in[10];
    const float* W_cls = (const float*)d_in[11];
    const float* b_cls = (const float*)d_in[12];
    float* out = (float*)d_out;

    char* ws = (char*)d_ws;
    size_t off = 0;
    auto alloc = [&](size_t bytes) -> void* {
        off = (off + 255) & ~(size_t)255;
        void* p = ws + off;
        off += bytes;
        return p;
    };
    float*          h    = (float*)alloc((size_t)NN * OD * 4);              // 25.6 MB
    unsigned short* hx   = (unsigned short*)alloc((size_t)NN * 256 * 2);    // 25.6 MB
    int*   deg4    = (int*)alloc((size_t)NN4 * 4);
    int*   rowp4   = (int*)alloc((size_t)(NN4 + 1) * 4);
    int*   cursor4 = (int*)alloc((size_t)NN4 * 4);
    int*   epk     = (int*)alloc((size_t)NE * 4);
    int*   bsum    = (int*)alloc(256 * 4);
    int*   gdeg    = (int*)alloc(NG * 4);
    int*   growp   = (int*)alloc((NG + 1) * 4);
    int*   gcur    = (int*)alloc(NG * 4);
    int*   nlist   = (int*)alloc((size_t)NN * 4);
    float* feats   = (float*)alloc((size_t)NG * 192 * 4);
    float* partial = (float*)alloc((size_t)NG * RC * 192 * 4);              // 393 KB
    unsigned short* Wcat = (unsigned short*)alloc((size_t)65536 * 2);       // 128 KB
    unsigned short* Wpk  = (unsigned short*)alloc((size_t)98304 * 2);       // 192 KB
    float*          bpk  = (float*)alloc(512 * 4);
    (void)ws_size; (void)in_sizes; (void)n_in; (void)out_size;

    hipMemsetAsync(deg4, 0, (size_t)NN4 * 4, stream);
    hipMemsetAsync(gdeg, 0, NG * 4, stream);

    k_cvtws<<<(65536 + 255) / 256, 256, 0, stream>>>(Ws, Wcat);
    k_pack<<<(98304 + 255) / 256, 256, 0, stream>>>(W_ih, W_hh, b_ih, b_hh, Wpk, bpk);

    k_init_h<<<(NN * OD + 255) / 256, 256, 0, stream>>>(nf, h, hx);

    // (dst, etype) CSR
    k_count<<<(NE + 255) / 256, 256, 0, stream>>>(dst, et, deg4);
    const int nb4 = (NN4 + 1023) / 1024;   // 196
    k_scan1<<<nb4, 1024, 0, stream>>>(deg4, rowp4, bsum, NN4);
    k_scan2<<<1, 256, 0, stream>>>(bsum, nb4);
    k_scan3<<<(NN4 + 255) / 256, 256, 0, stream>>>(deg4, bsum, rowp4, cursor4, NN4);
    k_fill<<<(NE + 255) / 256, 256, 0, stream>>>(src, dst, et, cursor4, epk);

    // graph CSR (readout)
    const int nbn = (NN + 1023) / 1024;    // 49
    k_gcount<<<nbn, 1024, 0, stream>>>(gid, gdeg);
    k_gscan<<<1, NG, 0, stream>>>(gdeg, growp, gcur);
    k_gfill<<<nbn, 1024, 0, stream>>>(gid, gcur, nlist);

    const int mt32 = (NN + 31) / 32;   // 1563 node tiles
    const int mt64 = (NN + 63) / 64;   // 782 node tiles
    for (int s = 0; s < 8; ++s) {
        k_agg_gemm<<<mt32, 256, 0, stream>>>(hx, rowp4, epk, deg4, Wcat, bs, hx);
        k_gates_gru<<<mt64, 512, 0, stream>>>(hx, Wpk, bpk, h, hx);
    }

    k_readout<<<NG * RC, 192, 0, stream>>>(h, nf, nlist, growp, partial);
    k_reduce<<<(NG * 192 + 255) / 256, 256, 0, stream>>>(partial, feats);
    k_final<<<1, 64, 0, stream>>>(feats, W_cls, b_cls, out);
}